// Round 8
// baseline (481.050 us; speedup 1.0000x reference)
//
#include <hip/hip_runtime.h>
#include <hip/hip_bf16.h>
#include <hip/hip_fp16.h>
#include <cstdint>

#define NREP 8

// ---------------- CSR build ----------------

// per-node: exclusive prefix across the 8 replica counts (in place); deg = total
__global__ void k_prefix(int* __restrict__ deg_r, int n, int* __restrict__ deg) {
    int i = blockIdx.x * blockDim.x + threadIdx.x;
    if (i >= n) return;
    int sum = 0;
#pragma unroll
    for (int r = 0; r < NREP; ++r) {
        int v = deg_r[r * n + i];
        deg_r[r * n + i] = sum;
        sum += v;
    }
    deg[i] = sum;
}

__global__ void k_scan1(const int* __restrict__ deg, int n, int* __restrict__ bsums) {
    __shared__ int s[256];
    int t = threadIdx.x;
    int i = blockIdx.x * 256 + t;
    int v = (i < n) ? deg[i] : 0;
    s[t] = v; __syncthreads();
    for (int off = 128; off > 0; off >>= 1) {
        if (t < off) s[t] += s[t + off];
        __syncthreads();
    }
    if (t == 0) bsums[blockIdx.x] = s[0];
}

// single block, inclusive->exclusive scan of up to 512 block sums
__global__ void k_scan2(const int* __restrict__ bsums, int nb, int* __restrict__ boffs) {
    __shared__ int s[512];
    int t = threadIdx.x;
    int v = (t < nb) ? bsums[t] : 0;
    s[t] = v; __syncthreads();
    for (int off = 1; off < 512; off <<= 1) {
        int nv = (t >= off) ? s[t - off] : 0;
        __syncthreads();
        s[t] += nv;
        __syncthreads();
    }
    if (t < nb) boffs[t] = s[t] - v;  // exclusive
}

// rowst from scanned deg; also fold rowst into the 8 replica prefixes -> absolute bases
__global__ void k_scan3(const int* __restrict__ deg, int n, const int* __restrict__ boffs,
                        int* __restrict__ rowst, int* __restrict__ deg_r) {
    __shared__ int s[256];
    int t = threadIdx.x;
    int i = blockIdx.x * 256 + t;
    int v = (i < n) ? deg[i] : 0;
    s[t] = v; __syncthreads();
    for (int off = 1; off < 256; off <<= 1) {
        int nv = (t >= off) ? s[t - off] : 0;
        __syncthreads();
        s[t] += nv;
        __syncthreads();
    }
    int incl = s[t] + boffs[blockIdx.x];
    if (i < n) {
        int ex = incl - v;
        rowst[i] = ex;
        if (i == n - 1) rowst[n] = incl;
#pragma unroll
        for (int r = 0; r < NREP; ++r) deg_r[r * n + i] += ex;
    }
}

// atomic-free scatter: position = base_r[rep][dst] + local_rank.
// 8 edges/thread; all loads/stores independent -> deep MLP.
__global__ void k_scatter(const int* __restrict__ src, const int* __restrict__ dst,
                          const int* __restrict__ rank, const int* __restrict__ deg_r,
                          int n, int E, int* __restrict__ col) {
    int t = blockIdx.x * blockDim.x + threadIdx.x;
    int base = t * 8;
    if (base + 8 <= E) {
        int4 d[2], s[2], r[2];
#pragma unroll
        for (int k = 0; k < 2; ++k) {
            d[k] = *reinterpret_cast<const int4*>(dst + base + k * 4);
            s[k] = *reinterpret_cast<const int4*>(src + base + k * 4);
            r[k] = *reinterpret_cast<const int4*>(rank + base + k * 4);
        }
        const int* dd = reinterpret_cast<const int*>(d);
        const int* ss = reinterpret_cast<const int*>(s);
        const int* rr = reinterpret_cast<const int*>(r);
        int p[8];
#pragma unroll
        for (int k = 0; k < 8; ++k)
            p[k] = deg_r[(rr[k] & (NREP - 1)) * n + dd[k]] + (rr[k] >> 3);
#pragma unroll
        for (int k = 0; k < 8; ++k) col[p[k]] = ss[k];
    } else {
        for (int i = base; i < E; ++i) {
            int rk = rank[i];
            col[deg_r[(rk & (NREP - 1)) * n + dst[i]] + (rk >> 3)] = src[i];
        }
    }
}

// ---------------- per-layer kernels ----------------

__device__ __forceinline__ float lane_bcast(float v, int k) {
    return __int_as_float(__builtin_amdgcn_readlane(__float_as_int(v), k));
}

// Fused: blocks [0,gemmBlocks) do GEMM+alpha; blocks beyond do the edge histogram
// into 8 replicated deg planes (replica = hist-block & 7), capturing local rank.
// Zero-LDS GEMM: each wave owns 16 nodes; lane holds W column pair in 64 VGPRs;
// x broadcast via readlane (static index, fully unrolled).
__global__ void __launch_bounds__(256)
k_gemm_alpha(const float* __restrict__ x, const float* __restrict__ W,
             const float* __restrict__ a_src, const float* __restrict__ a_dst,
             __half* __restrict__ h16, float* __restrict__ alpha_src,
             float* __restrict__ alpha_dst, int n,
             const int* __restrict__ dstv, int E, int* __restrict__ deg_r,
             int* __restrict__ rank, int gemmBlocks) {
    if ((int)blockIdx.x >= gemmBlocks) {
        // 16 edges/thread histogram; atomic return = local rank within replica
        int b = blockIdx.x - gemmBlocks;
        int rep = b & (NREP - 1);
        int* degp = deg_r + (size_t)rep * n;
        int base = (b * 256 + threadIdx.x) * 16;
        if (base + 16 <= E) {
            int4 d[4];
#pragma unroll
            for (int k = 0; k < 4; ++k)
                d[k] = *reinterpret_cast<const int4*>(dstv + base + k * 4);
            const int* dd = reinterpret_cast<const int*>(d);
            int r[16];
#pragma unroll
            for (int k = 0; k < 16; ++k) r[k] = (atomicAdd(&degp[dd[k]], 1) << 3) | rep;
#pragma unroll
            for (int k = 0; k < 4; ++k)
                *reinterpret_cast<int4*>(rank + base + k * 4) =
                    *reinterpret_cast<const int4*>(r + k * 4);
        } else {
            for (int i = base; i < E; ++i)
                rank[i] = (atomicAdd(&degp[dstv[i]], 1) << 3) | rep;
        }
        return;
    }
    int lane = threadIdx.x & 63;
    int wave = threadIdx.x >> 6;
    int j2 = lane * 2;              // flattened out channel pair = head*32 + c
    int nbase = blockIdx.x * 64 + wave * 16;

    // W column pair -> 64 VGPRs (32 x float2); att vectors -> 4 regs
    float2 wr[32];
#pragma unroll
    for (int k = 0; k < 32; ++k)
        wr[k] = *reinterpret_cast<const float2*>(W + k * 128 + j2);
    float2 as2 = *reinterpret_cast<const float2*>(a_src + j2);
    float2 ad2 = *reinterpret_cast<const float2*>(a_dst + j2);

    // x rows for the 16 nodes: one VGPR each (lane&31 -> channel)
    float xr[16];
#pragma unroll
    for (int m = 0; m < 16; ++m) {
        int node = nbase + m;
        xr[m] = (node < n) ? x[(size_t)node * 32 + (lane & 31)] : 0.f;
    }

#pragma unroll
    for (int m = 0; m < 16; ++m) {
        int node = nbase + m;
        if (node >= n) continue;     // wave-uniform guard
        float acc0 = 0.f, acc1 = 0.f;
#pragma unroll
        for (int k = 0; k < 32; ++k) {
            float xv = lane_bcast(xr[m], k);      // x[node][k] via readlane (SGPR)
            acc0 += xv * wr[k].x;
            acc1 += xv * wr[k].y;
        }
        *reinterpret_cast<__half2*>(h16 + (size_t)node * 128 + j2) =
            __floats2half2_rn(acc0, acc1);
        float ps = acc0 * as2.x + acc1 * as2.y;
        float pd = acc0 * ad2.x + acc1 * ad2.y;
#pragma unroll
        for (int mm = 1; mm < 16; mm <<= 1) {
            ps += __shfl_xor(ps, mm, 64);
            pd += __shfl_xor(pd, mm, 64);
        }
        if ((lane & 15) == 0) {
            int head = lane >> 4;
            alpha_src[node * 4 + head] = ps;
            alpha_dst[node * 4 + head] = pd;
        }
    }
}

__device__ __forceinline__ float lrelu_exp(float e) {
    e = e > 0.f ? e : 0.2f * e;
    return __expf(e);
}

__device__ __forceinline__ float4 h16_to_f4(uint2 v) {
    float2 fa = __half22float2(*reinterpret_cast<__half2*>(&v.x));
    float2 fb = __half22float2(*reinterpret_cast<__half2*>(&v.y));
    return make_float4(fa.x, fa.y, fb.x, fb.y);
}

// one wave per dst node; two edges in flight per gather step (one per half-wave),
// fp16 h rows (256B), uint2 (8B) loads; unroll x4 => 8 edge rows in flight per wave.
// single-pass softmax (no max-shift) + self loop + head-mean + bias + elu.
__global__ void k_agg(const __half* __restrict__ h16, const float* __restrict__ asrc,
                      const float* __restrict__ adst, const int* __restrict__ rowst,
                      const int* __restrict__ col, const float* __restrict__ bias,
                      float* __restrict__ out, int n) {
    int wid = (int)((blockIdx.x * (size_t)blockDim.x + threadIdx.x) >> 6);
    if (wid >= n) return;
    int lane = threadIdx.x & 63;
    int half = lane >> 5;       // which edge of the pair this half-wave handles
    int q = lane & 31;          // channel quad: flattened channels 4q..4q+3
    int head = q >> 3;
    float ad = adst[wid * 4 + head];

    float4 acc = make_float4(0.f, 0.f, 0.f, 0.f);
    float s = 0.f;
    if (half == 0) {  // self loop counted once
        float w = lrelu_exp(asrc[wid * 4 + head] + ad);
        uint2 v = *reinterpret_cast<const uint2*>(h16 + (size_t)wid * 128 + q * 4);
        float4 hv = h16_to_f4(v);
        s = w;
        acc.x = w * hv.x; acc.y = w * hv.y; acc.z = w * hv.z; acc.w = w * hv.w;
    }

    int beg = rowst[wid], end = rowst[wid + 1];
    int i = beg;
    for (; i + 8 <= end; i += 8) {
        int base = i + half * 4;
        int s0 = col[base], s1 = col[base + 1], s2 = col[base + 2], s3 = col[base + 3];
        float x0 = asrc[s0 * 4 + head];
        float x1 = asrc[s1 * 4 + head];
        float x2 = asrc[s2 * 4 + head];
        float x3 = asrc[s3 * 4 + head];
        uint2 v0 = *reinterpret_cast<const uint2*>(h16 + (size_t)s0 * 128 + q * 4);
        uint2 v1 = *reinterpret_cast<const uint2*>(h16 + (size_t)s1 * 128 + q * 4);
        uint2 v2 = *reinterpret_cast<const uint2*>(h16 + (size_t)s2 * 128 + q * 4);
        uint2 v3 = *reinterpret_cast<const uint2*>(h16 + (size_t)s3 * 128 + q * 4);
        float w0 = lrelu_exp(x0 + ad);
        float w1 = lrelu_exp(x1 + ad);
        float w2 = lrelu_exp(x2 + ad);
        float w3 = lrelu_exp(x3 + ad);
        float4 h0 = h16_to_f4(v0), h1 = h16_to_f4(v1), h2 = h16_to_f4(v2), h3 = h16_to_f4(v3);
        s += w0 + w1 + w2 + w3;
        acc.x += w0 * h0.x + w1 * h1.x + w2 * h2.x + w3 * h3.x;
        acc.y += w0 * h0.y + w1 * h1.y + w2 * h2.y + w3 * h3.y;
        acc.z += w0 * h0.z + w1 * h1.z + w2 * h2.z + w3 * h3.z;
        acc.w += w0 * h0.w + w1 * h1.w + w2 * h2.w + w3 * h3.w;
    }
    for (; i + 2 <= end; i += 2) {
        int sidx = col[i + half];
        float w = lrelu_exp(asrc[sidx * 4 + head] + ad);
        float4 hv = h16_to_f4(*reinterpret_cast<const uint2*>(h16 + (size_t)sidx * 128 + q * 4));
        s += w;
        acc.x += w * hv.x; acc.y += w * hv.y; acc.z += w * hv.z; acc.w += w * hv.w;
    }
    if (i < end && half == 0) {   // odd remainder: half 0 only
        int sidx = col[i];
        float w = lrelu_exp(asrc[sidx * 4 + head] + ad);
        float4 hv = h16_to_f4(*reinterpret_cast<const uint2*>(h16 + (size_t)sidx * 128 + q * 4));
        s += w;
        acc.x += w * hv.x; acc.y += w * hv.y; acc.z += w * hv.z; acc.w += w * hv.w;
    }

    // combine the two half-wave partials
    s += __shfl_xor(s, 32, 64);
    acc.x += __shfl_xor(acc.x, 32, 64);
    acc.y += __shfl_xor(acc.y, 32, 64);
    acc.z += __shfl_xor(acc.z, 32, 64);
    acc.w += __shfl_xor(acc.w, 32, 64);
    float inv = 1.f / s;
    acc.x *= inv; acc.y *= inv; acc.z *= inv; acc.w *= inv;
    // head mean: lanes q, q^8, q^16, q^24 hold heads 0..3 of channel group q&7
    acc.x += __shfl_xor(acc.x, 8, 64);  acc.x += __shfl_xor(acc.x, 16, 64);
    acc.y += __shfl_xor(acc.y, 8, 64);  acc.y += __shfl_xor(acc.y, 16, 64);
    acc.z += __shfl_xor(acc.z, 8, 64);  acc.z += __shfl_xor(acc.z, 16, 64);
    acc.w += __shfl_xor(acc.w, 8, 64);  acc.w += __shfl_xor(acc.w, 16, 64);
    if (lane < 8) {
        float4 b4 = *reinterpret_cast<const float4*>(&bias[lane * 4]);
        float o0 = acc.x * 0.25f + b4.x;
        float o1 = acc.y * 0.25f + b4.y;
        float o2 = acc.z * 0.25f + b4.z;
        float o3 = acc.w * 0.25f + b4.w;
        o0 = o0 > 0.f ? o0 : (__expf(o0) - 1.f);
        o1 = o1 > 0.f ? o1 : (__expf(o1) - 1.f);
        o2 = o2 > 0.f ? o2 : (__expf(o2) - 1.f);
        o3 = o3 > 0.f ? o3 : (__expf(o3) - 1.f);
        *reinterpret_cast<float4*>(&out[(size_t)wid * 32 + lane * 4]) =
            make_float4(o0, o1, o2, o3);
    }
}

// ---------------- launch ----------------

extern "C" void kernel_launch(void* const* d_in, const int* in_sizes, int n_in,
                              void* d_out, int out_size, void* d_ws, size_t ws_size,
                              hipStream_t stream) {
    const float* x       = (const float*)d_in[0];
    const int*   ei      = (const int*)d_in[1];   // [2,E] int32
    const float* Ws      = (const float*)d_in[3]; // [3,32,128]
    const float* att_src = (const float*)d_in[4]; // [3,4,32]
    const float* att_dst = (const float*)d_in[5];
    const float* bias    = (const float*)d_in[6]; // [3,32]

    int N = in_sizes[0] / 32;
    int E = in_sizes[1] / 2;
    const int* srcv = ei;
    const int* dstv = ei + E;

    // workspace layout (~58MB)
    float* fws   = (float*)d_ws;
    __half* h16  = (__half*)fws;                        // N*128 halves
    float* asrc  = (float*)(h16 + (size_t)N * 128);     // N*4
    float* adst  = asrc + (size_t)N * 4;                // N*4
    float* xbuf  = adst + (size_t)N * 4;                // N*32
    int*   deg_r  = (int*)(xbuf + (size_t)N * 32);      // NREP*N
    int*   deg    = deg_r + (size_t)NREP * N;           // N
    int*   rowst  = deg + N;                            // N+1
    int*   bsums  = rowst + N + 1;                      // 512
    int*   boffs  = bsums + 512;                        // 512
    int*   col    = boffs + 512;                        // E
    int*   rank   = col + E;                            // E

    int nb256 = (N + 255) / 256;           // <=512 for scan2
    int gemmBlocks = (N + 63) / 64;
    int histBlocks = (E + 16 * 256 - 1) / (16 * 256);
    int edgeBlocks8 = (E + 8 * 256 - 1) / (8 * 256);

    hipMemsetAsync(deg_r, 0, (size_t)NREP * N * sizeof(int), stream);

    for (int l = 0; l < 3; ++l) {
        const float* xin = (l == 0) ? x : xbuf;
        float* xout = (l == 2) ? (float*)d_out : xbuf;
        int extra = (l == 0) ? histBlocks : 0;
        k_gemm_alpha<<<gemmBlocks + extra, 256, 0, stream>>>(
            xin, Ws + (size_t)l * 32 * 128, att_src + l * 128, att_dst + l * 128,
            h16, asrc, adst, N, dstv, E, deg_r, rank, gemmBlocks);
        if (l == 0) {
            k_prefix<<<nb256, 256, 0, stream>>>(deg_r, N, deg);
            k_scan1<<<nb256, 256, 0, stream>>>(deg, N, bsums);
            k_scan2<<<1, 512, 0, stream>>>(bsums, nb256, boffs);
            k_scan3<<<nb256, 256, 0, stream>>>(deg, N, boffs, rowst, deg_r);
            k_scatter<<<edgeBlocks8, 256, 0, stream>>>(srcv, dstv, rank, deg_r, N, E, col);
        }
        k_agg<<<(N + 3) / 4, 256, 0, stream>>>(
            h16, asrc, adst, rowst, col, bias + l * 32, xout, N);
    }
}

// Round 9
// 437.684 us; speedup vs baseline: 1.0991x; 1.0991x over previous
//
#include <hip/hip_runtime.h>
#include <hip/hip_bf16.h>
#include <hip/hip_fp16.h>
#include <cstdint>

// ---------------- CSR build ----------------

__global__ void k_scan1(const int* __restrict__ deg, int n, int* __restrict__ bsums) {
    __shared__ int s[256];
    int t = threadIdx.x;
    int i = blockIdx.x * 256 + t;
    int v = (i < n) ? deg[i] : 0;
    s[t] = v; __syncthreads();
    for (int off = 128; off > 0; off >>= 1) {
        if (t < off) s[t] += s[t + off];
        __syncthreads();
    }
    if (t == 0) bsums[blockIdx.x] = s[0];
}

// single block, inclusive->exclusive scan of up to 512 block sums
__global__ void k_scan2(const int* __restrict__ bsums, int nb, int* __restrict__ boffs) {
    __shared__ int s[512];
    int t = threadIdx.x;
    int v = (t < nb) ? bsums[t] : 0;
    s[t] = v; __syncthreads();
    for (int off = 1; off < 512; off <<= 1) {
        int nv = (t >= off) ? s[t - off] : 0;
        __syncthreads();
        s[t] += nv;
        __syncthreads();
    }
    if (t < nb) boffs[t] = s[t] - v;  // exclusive
}

__global__ void k_scan3(const int* __restrict__ deg, int n, const int* __restrict__ boffs,
                        int* __restrict__ rowst) {
    __shared__ int s[256];
    int t = threadIdx.x;
    int i = blockIdx.x * 256 + t;
    int v = (i < n) ? deg[i] : 0;
    s[t] = v; __syncthreads();
    for (int off = 1; off < 256; off <<= 1) {
        int nv = (t >= off) ? s[t - off] : 0;
        __syncthreads();
        s[t] += nv;
        __syncthreads();
    }
    int incl = s[t] + boffs[blockIdx.x];
    if (i < n) {
        rowst[i] = incl - v;
        if (i == n - 1) rowst[n] = incl;
    }
}

// atomic-free scatter: position = rowst[dst] + rank (rank captured during hist).
// 16 edges/thread; all loads/stores independent -> deep MLP.
__global__ void k_scatter(const int* __restrict__ src, const int* __restrict__ dst,
                          const int* __restrict__ rank, const int* __restrict__ rowst,
                          int E, int* __restrict__ col) {
    int t = blockIdx.x * blockDim.x + threadIdx.x;
    int base = t * 16;
    if (base + 16 <= E) {
        int4 d[4], s[4], r[4];
#pragma unroll
        for (int k = 0; k < 4; ++k) {
            d[k] = *reinterpret_cast<const int4*>(dst + base + k * 4);
            s[k] = *reinterpret_cast<const int4*>(src + base + k * 4);
            r[k] = *reinterpret_cast<const int4*>(rank + base + k * 4);
        }
        const int* dd = reinterpret_cast<const int*>(d);
        const int* ss = reinterpret_cast<const int*>(s);
        const int* rr = reinterpret_cast<const int*>(r);
        int p[16];
#pragma unroll
        for (int k = 0; k < 16; ++k) p[k] = rowst[dd[k]] + rr[k];
#pragma unroll
        for (int k = 0; k < 16; ++k) col[p[k]] = ss[k];
    } else {
        for (int i = base; i < E; ++i) col[rowst[dst[i]] + rank[i]] = src[i];
    }
}

// ---------------- per-layer kernels ----------------

__device__ __forceinline__ float lane_bcast(float v, int k) {
    return __int_as_float(__builtin_amdgcn_readlane(__float_as_int(v), k));
}

// Fused: blocks [0,gemmBlocks) do GEMM+alpha; blocks beyond do the edge histogram
// AND capture each edge's rank within its dst segment (layer 0 only).
// Hist: 32 edges/thread -> 32 independent atomics in flight per thread
// (memory-side atomic units reward deep per-thread batching: 16/thr=93us,
//  8/thr=130us measured; replication across planes was useless).
// Zero-LDS GEMM: each wave owns 16 nodes; lane holds W column pair in 64 VGPRs;
// x broadcast via readlane (static index, fully unrolled).
__global__ void __launch_bounds__(256)
k_gemm_alpha(const float* __restrict__ x, const float* __restrict__ W,
             const float* __restrict__ a_src, const float* __restrict__ a_dst,
             __half* __restrict__ h16, float* __restrict__ alpha_src,
             float* __restrict__ alpha_dst, int n,
             const int* __restrict__ dstv, int E, int* __restrict__ deg,
             int* __restrict__ rank, int gemmBlocks) {
    if ((int)blockIdx.x >= gemmBlocks) {
        int b = blockIdx.x - gemmBlocks;
        int base = (b * 256 + threadIdx.x) * 32;
        if (base + 32 <= E) {
            int4 d[8];
#pragma unroll
            for (int k = 0; k < 8; ++k)
                d[k] = *reinterpret_cast<const int4*>(dstv + base + k * 4);
            const int* dd = reinterpret_cast<const int*>(d);
            int r[32];
#pragma unroll
            for (int k = 0; k < 32; ++k) r[k] = atomicAdd(&deg[dd[k]], 1);
#pragma unroll
            for (int k = 0; k < 8; ++k)
                *reinterpret_cast<int4*>(rank + base + k * 4) =
                    *reinterpret_cast<const int4*>(r + k * 4);
        } else {
            for (int i = base; i < E; ++i) rank[i] = atomicAdd(&deg[dstv[i]], 1);
        }
        return;
    }
    int lane = threadIdx.x & 63;
    int wave = threadIdx.x >> 6;
    int j2 = lane * 2;              // flattened out channel pair = head*32 + c
    int nbase = blockIdx.x * 64 + wave * 16;

    // W column pair -> 64 VGPRs (32 x float2); att vectors -> 4 regs
    float2 wr[32];
#pragma unroll
    for (int k = 0; k < 32; ++k)
        wr[k] = *reinterpret_cast<const float2*>(W + k * 128 + j2);
    float2 as2 = *reinterpret_cast<const float2*>(a_src + j2);
    float2 ad2 = *reinterpret_cast<const float2*>(a_dst + j2);

    // x rows for the 16 nodes: one VGPR each (lane&31 -> channel)
    float xr[16];
#pragma unroll
    for (int m = 0; m < 16; ++m) {
        int node = nbase + m;
        xr[m] = (node < n) ? x[(size_t)node * 32 + (lane & 31)] : 0.f;
    }

#pragma unroll
    for (int m = 0; m < 16; ++m) {
        int node = nbase + m;
        if (node >= n) continue;     // wave-uniform guard
        float acc0 = 0.f, acc1 = 0.f;
#pragma unroll
        for (int k = 0; k < 32; ++k) {
            float xv = lane_bcast(xr[m], k);      // x[node][k] via readlane (SGPR)
            acc0 += xv * wr[k].x;
            acc1 += xv * wr[k].y;
        }
        *reinterpret_cast<__half2*>(h16 + (size_t)node * 128 + j2) =
            __floats2half2_rn(acc0, acc1);
        float ps = acc0 * as2.x + acc1 * as2.y;
        float pd = acc0 * ad2.x + acc1 * ad2.y;
#pragma unroll
        for (int mm = 1; mm < 16; mm <<= 1) {
            ps += __shfl_xor(ps, mm, 64);
            pd += __shfl_xor(pd, mm, 64);
        }
        if ((lane & 15) == 0) {
            int head = lane >> 4;
            alpha_src[node * 4 + head] = ps;
            alpha_dst[node * 4 + head] = pd;
        }
    }
}

__device__ __forceinline__ float lrelu_exp(float e) {
    e = e > 0.f ? e : 0.2f * e;
    return __expf(e);
}

__device__ __forceinline__ float4 h16_to_f4(uint2 v) {
    float2 fa = __half22float2(*reinterpret_cast<__half2*>(&v.x));
    float2 fb = __half22float2(*reinterpret_cast<__half2*>(&v.y));
    return make_float4(fa.x, fa.y, fb.x, fb.y);
}

// one wave per dst node; two edges in flight per gather step (one per half-wave),
// fp16 h rows (256B), uint2 (8B) loads; unroll x4 => 8 edge rows in flight per wave.
// single-pass softmax (no max-shift) + self loop + head-mean + bias + elu.
__global__ void k_agg(const __half* __restrict__ h16, const float* __restrict__ asrc,
                      const float* __restrict__ adst, const int* __restrict__ rowst,
                      const int* __restrict__ col, const float* __restrict__ bias,
                      float* __restrict__ out, int n) {
    int wid = (int)((blockIdx.x * (size_t)blockDim.x + threadIdx.x) >> 6);
    if (wid >= n) return;
    int lane = threadIdx.x & 63;
    int half = lane >> 5;       // which edge of the pair this half-wave handles
    int q = lane & 31;          // channel quad: flattened channels 4q..4q+3
    int head = q >> 3;
    float ad = adst[wid * 4 + head];

    float4 acc = make_float4(0.f, 0.f, 0.f, 0.f);
    float s = 0.f;
    if (half == 0) {  // self loop counted once
        float w = lrelu_exp(asrc[wid * 4 + head] + ad);
        uint2 v = *reinterpret_cast<const uint2*>(h16 + (size_t)wid * 128 + q * 4);
        float4 hv = h16_to_f4(v);
        s = w;
        acc.x = w * hv.x; acc.y = w * hv.y; acc.z = w * hv.z; acc.w = w * hv.w;
    }

    int beg = rowst[wid], end = rowst[wid + 1];
    int i = beg;
    for (; i + 8 <= end; i += 8) {
        int base = i + half * 4;
        int s0 = col[base], s1 = col[base + 1], s2 = col[base + 2], s3 = col[base + 3];
        float x0 = asrc[s0 * 4 + head];
        float x1 = asrc[s1 * 4 + head];
        float x2 = asrc[s2 * 4 + head];
        float x3 = asrc[s3 * 4 + head];
        uint2 v0 = *reinterpret_cast<const uint2*>(h16 + (size_t)s0 * 128 + q * 4);
        uint2 v1 = *reinterpret_cast<const uint2*>(h16 + (size_t)s1 * 128 + q * 4);
        uint2 v2 = *reinterpret_cast<const uint2*>(h16 + (size_t)s2 * 128 + q * 4);
        uint2 v3 = *reinterpret_cast<const uint2*>(h16 + (size_t)s3 * 128 + q * 4);
        float w0 = lrelu_exp(x0 + ad);
        float w1 = lrelu_exp(x1 + ad);
        float w2 = lrelu_exp(x2 + ad);
        float w3 = lrelu_exp(x3 + ad);
        float4 h0 = h16_to_f4(v0), h1 = h16_to_f4(v1), h2 = h16_to_f4(v2), h3 = h16_to_f4(v3);
        s += w0 + w1 + w2 + w3;
        acc.x += w0 * h0.x + w1 * h1.x + w2 * h2.x + w3 * h3.x;
        acc.y += w0 * h0.y + w1 * h1.y + w2 * h2.y + w3 * h3.y;
        acc.z += w0 * h0.z + w1 * h1.z + w2 * h2.z + w3 * h3.z;
        acc.w += w0 * h0.w + w1 * h1.w + w2 * h2.w + w3 * h3.w;
    }
    for (; i + 2 <= end; i += 2) {
        int sidx = col[i + half];
        float w = lrelu_exp(asrc[sidx * 4 + head] + ad);
        float4 hv = h16_to_f4(*reinterpret_cast<const uint2*>(h16 + (size_t)sidx * 128 + q * 4));
        s += w;
        acc.x += w * hv.x; acc.y += w * hv.y; acc.z += w * hv.z; acc.w += w * hv.w;
    }
    if (i < end && half == 0) {   // odd remainder: half 0 only
        int sidx = col[i];
        float w = lrelu_exp(asrc[sidx * 4 + head] + ad);
        float4 hv = h16_to_f4(*reinterpret_cast<const uint2*>(h16 + (size_t)sidx * 128 + q * 4));
        s += w;
        acc.x += w * hv.x; acc.y += w * hv.y; acc.z += w * hv.z; acc.w += w * hv.w;
    }

    // combine the two half-wave partials
    s += __shfl_xor(s, 32, 64);
    acc.x += __shfl_xor(acc.x, 32, 64);
    acc.y += __shfl_xor(acc.y, 32, 64);
    acc.z += __shfl_xor(acc.z, 32, 64);
    acc.w += __shfl_xor(acc.w, 32, 64);
    float inv = 1.f / s;
    acc.x *= inv; acc.y *= inv; acc.z *= inv; acc.w *= inv;
    // head mean: lanes q, q^8, q^16, q^24 hold heads 0..3 of channel group q&7
    acc.x += __shfl_xor(acc.x, 8, 64);  acc.x += __shfl_xor(acc.x, 16, 64);
    acc.y += __shfl_xor(acc.y, 8, 64);  acc.y += __shfl_xor(acc.y, 16, 64);
    acc.z += __shfl_xor(acc.z, 8, 64);  acc.z += __shfl_xor(acc.z, 16, 64);
    acc.w += __shfl_xor(acc.w, 8, 64);  acc.w += __shfl_xor(acc.w, 16, 64);
    if (lane < 8) {
        float4 b4 = *reinterpret_cast<const float4*>(&bias[lane * 4]);
        float o0 = acc.x * 0.25f + b4.x;
        float o1 = acc.y * 0.25f + b4.y;
        float o2 = acc.z * 0.25f + b4.z;
        float o3 = acc.w * 0.25f + b4.w;
        o0 = o0 > 0.f ? o0 : (__expf(o0) - 1.f);
        o1 = o1 > 0.f ? o1 : (__expf(o1) - 1.f);
        o2 = o2 > 0.f ? o2 : (__expf(o2) - 1.f);
        o3 = o3 > 0.f ? o3 : (__expf(o3) - 1.f);
        *reinterpret_cast<float4*>(&out[(size_t)wid * 32 + lane * 4]) =
            make_float4(o0, o1, o2, o3);
    }
}

// ---------------- launch ----------------

extern "C" void kernel_launch(void* const* d_in, const int* in_sizes, int n_in,
                              void* d_out, int out_size, void* d_ws, size_t ws_size,
                              hipStream_t stream) {
    const float* x       = (const float*)d_in[0];
    const int*   ei      = (const int*)d_in[1];   // [2,E] int32
    const float* Ws      = (const float*)d_in[3]; // [3,32,128]
    const float* att_src = (const float*)d_in[4]; // [3,4,32]
    const float* att_dst = (const float*)d_in[5];
    const float* bias    = (const float*)d_in[6]; // [3,32]

    int N = in_sizes[0] / 32;
    int E = in_sizes[1] / 2;
    const int* srcv = ei;
    const int* dstv = ei + E;

    // workspace layout
    float* fws   = (float*)d_ws;
    __half* h16  = (__half*)fws;                        // N*128 halves
    float* asrc  = (float*)(h16 + (size_t)N * 128);     // N*4
    float* adst  = asrc + (size_t)N * 4;                // N*4
    float* xbuf  = adst + (size_t)N * 4;                // N*32
    int*   deg    = (int*)(xbuf + (size_t)N * 32);      // N
    int*   rowst  = deg + N;                            // N+1
    int*   bsums  = rowst + N + 1;                      // 512
    int*   boffs  = bsums + 512;                        // 512
    int*   col    = boffs + 512;                        // E
    int*   rank   = col + E;                            // E

    int nb256 = (N + 255) / 256;           // <=512 for scan2
    int gemmBlocks = (N + 63) / 64;
    int histBlocks = (E + 32 * 256 - 1) / (32 * 256);
    int scatBlocks = (E + 16 * 256 - 1) / (16 * 256);

    hipMemsetAsync(deg, 0, (size_t)N * sizeof(int), stream);

    for (int l = 0; l < 3; ++l) {
        const float* xin = (l == 0) ? x : xbuf;
        float* xout = (l == 2) ? (float*)d_out : xbuf;
        int extra = (l == 0) ? histBlocks : 0;
        k_gemm_alpha<<<gemmBlocks + extra, 256, 0, stream>>>(
            xin, Ws + (size_t)l * 32 * 128, att_src + l * 128, att_dst + l * 128,
            h16, asrc, adst, N, dstv, E, deg, rank, gemmBlocks);
        if (l == 0) {
            k_scan1<<<nb256, 256, 0, stream>>>(deg, N, bsums);
            k_scan2<<<1, 512, 0, stream>>>(bsums, nb256, boffs);
            k_scan3<<<nb256, 256, 0, stream>>>(deg, N, boffs, rowst);
            k_scatter<<<scatBlocks, 256, 0, stream>>>(srcv, dstv, rank, rowst, E, col);
        }
        k_agg<<<(N + 3) / 4, 256, 0, stream>>>(
            h16, asrc, adst, rowst, col, bias + l * 32, xout, N);
    }
}

// Round 10
// 426.515 us; speedup vs baseline: 1.1279x; 1.0262x over previous
//
#include <hip/hip_runtime.h>
#include <hip/hip_bf16.h>
#include <hip/hip_fp16.h>
#include <cstdint>

// ---------------- CSR build ----------------

__global__ void k_scan1(const int* __restrict__ deg, int n, int* __restrict__ bsums) {
    __shared__ int s[256];
    int t = threadIdx.x;
    int i = blockIdx.x * 256 + t;
    int v = (i < n) ? deg[i] : 0;
    s[t] = v; __syncthreads();
    for (int off = 128; off > 0; off >>= 1) {
        if (t < off) s[t] += s[t + off];
        __syncthreads();
    }
    if (t == 0) bsums[blockIdx.x] = s[0];
}

// single block, inclusive->exclusive scan of up to 512 block sums
__global__ void k_scan2(const int* __restrict__ bsums, int nb, int* __restrict__ boffs) {
    __shared__ int s[512];
    int t = threadIdx.x;
    int v = (t < nb) ? bsums[t] : 0;
    s[t] = v; __syncthreads();
    for (int off = 1; off < 512; off <<= 1) {
        int nv = (t >= off) ? s[t - off] : 0;
        __syncthreads();
        s[t] += nv;
        __syncthreads();
    }
    if (t < nb) boffs[t] = s[t] - v;  // exclusive
}

__global__ void k_scan3(const int* __restrict__ deg, int n, const int* __restrict__ boffs,
                        int* __restrict__ rowst) {
    __shared__ int s[256];
    int t = threadIdx.x;
    int i = blockIdx.x * 256 + t;
    int v = (i < n) ? deg[i] : 0;
    s[t] = v; __syncthreads();
    for (int off = 1; off < 256; off <<= 1) {
        int nv = (t >= off) ? s[t - off] : 0;
        __syncthreads();
        s[t] += nv;
        __syncthreads();
    }
    int incl = s[t] + boffs[blockIdx.x];
    if (i < n) {
        rowst[i] = incl - v;
        if (i == n - 1) rowst[n] = incl;
    }
}

// atomic-free scatter: position = rowst[dst] + rank (rank captured during hist).
// 16 edges/thread; all loads/stores independent -> deep MLP.
__global__ void k_scatter(const int* __restrict__ src, const int* __restrict__ dst,
                          const int* __restrict__ rank, const int* __restrict__ rowst,
                          int E, int* __restrict__ col) {
    int t = blockIdx.x * blockDim.x + threadIdx.x;
    int base = t * 16;
    if (base + 16 <= E) {
        int4 d[4], s[4], r[4];
#pragma unroll
        for (int k = 0; k < 4; ++k) {
            d[k] = *reinterpret_cast<const int4*>(dst + base + k * 4);
            s[k] = *reinterpret_cast<const int4*>(src + base + k * 4);
            r[k] = *reinterpret_cast<const int4*>(rank + base + k * 4);
        }
        const int* dd = reinterpret_cast<const int*>(d);
        const int* ss = reinterpret_cast<const int*>(s);
        const int* rr = reinterpret_cast<const int*>(r);
        int p[16];
#pragma unroll
        for (int k = 0; k < 16; ++k) p[k] = rowst[dd[k]] + rr[k];
#pragma unroll
        for (int k = 0; k < 16; ++k) col[p[k]] = ss[k];
    } else {
        for (int i = base; i < E; ++i) col[rowst[dst[i]] + rank[i]] = src[i];
    }
}

// ---------------- per-layer kernels ----------------

__device__ __forceinline__ float lane_bcast(float v, int k) {
    return __int_as_float(__builtin_amdgcn_readlane(__float_as_int(v), k));
}

// Fused: blocks [0,gemmBlocks) do GEMM+alpha; blocks beyond do the edge histogram
// AND capture each edge's rank within its dst segment (layer 0 only).
// Hist: 32 edges/thread -> 32 independent atomics in flight per thread
// (memory-side atomic wall ~20/ns; batching depth is the only knob that matters).
__global__ void __launch_bounds__(256)
k_gemm_alpha(const float* __restrict__ x, const float* __restrict__ W,
             const float* __restrict__ a_src, const float* __restrict__ a_dst,
             __half* __restrict__ h16, float* __restrict__ alpha_src,
             float* __restrict__ alpha_dst, int n,
             const int* __restrict__ dstv, int E, int* __restrict__ deg,
             int* __restrict__ rank, int gemmBlocks) {
    if ((int)blockIdx.x >= gemmBlocks) {
        int b = blockIdx.x - gemmBlocks;
        int base = (b * 256 + threadIdx.x) * 32;
        if (base + 32 <= E) {
            int4 d[8];
#pragma unroll
            for (int k = 0; k < 8; ++k)
                d[k] = *reinterpret_cast<const int4*>(dstv + base + k * 4);
            const int* dd = reinterpret_cast<const int*>(d);
            int r[32];
#pragma unroll
            for (int k = 0; k < 32; ++k) r[k] = atomicAdd(&deg[dd[k]], 1);
#pragma unroll
            for (int k = 0; k < 8; ++k)
                *reinterpret_cast<int4*>(rank + base + k * 4) =
                    *reinterpret_cast<const int4*>(r + k * 4);
        } else {
            for (int i = base; i < E; ++i) rank[i] = atomicAdd(&deg[dstv[i]], 1);
        }
        return;
    }
    int lane = threadIdx.x & 63;
    int wave = threadIdx.x >> 6;
    int j2 = lane * 2;              // flattened out channel pair = head*32 + c
    int nbase = blockIdx.x * 64 + wave * 16;

    // W column pair -> 64 VGPRs (32 x float2); att vectors -> 4 regs
    float2 wr[32];
#pragma unroll
    for (int k = 0; k < 32; ++k)
        wr[k] = *reinterpret_cast<const float2*>(W + k * 128 + j2);
    float2 as2 = *reinterpret_cast<const float2*>(a_src + j2);
    float2 ad2 = *reinterpret_cast<const float2*>(a_dst + j2);

    // x rows for the 16 nodes: one VGPR each (lane&31 -> channel)
    float xr[16];
#pragma unroll
    for (int m = 0; m < 16; ++m) {
        int node = nbase + m;
        xr[m] = (node < n) ? x[(size_t)node * 32 + (lane & 31)] : 0.f;
    }

#pragma unroll
    for (int m = 0; m < 16; ++m) {
        int node = nbase + m;
        if (node >= n) continue;     // wave-uniform guard
        float acc0 = 0.f, acc1 = 0.f;
#pragma unroll
        for (int k = 0; k < 32; ++k) {
            float xv = lane_bcast(xr[m], k);      // x[node][k] via readlane (SGPR)
            acc0 += xv * wr[k].x;
            acc1 += xv * wr[k].y;
        }
        *reinterpret_cast<__half2*>(h16 + (size_t)node * 128 + j2) =
            __floats2half2_rn(acc0, acc1);
        float ps = acc0 * as2.x + acc1 * as2.y;
        float pd = acc0 * ad2.x + acc1 * ad2.y;
#pragma unroll
        for (int mm = 1; mm < 16; mm <<= 1) {
            ps += __shfl_xor(ps, mm, 64);
            pd += __shfl_xor(pd, mm, 64);
        }
        if ((lane & 15) == 0) {
            int head = lane >> 4;
            alpha_src[node * 4 + head] = ps;
            alpha_dst[node * 4 + head] = pd;
        }
    }
}

__device__ __forceinline__ float lrelu_exp(float e) {
    e = e > 0.f ? e : 0.2f * e;
    return __expf(e);
}

// one wave per dst node; 4 edges per wave via 16-lane groups, 2 edges in flight
// per group (8 rows in flight/wave). Lane q loads uint4 = 8 fp16 channels
// (8q..8q+7 flattened, head = q>>2). single-pass softmax + self loop +
// head-mean + bias + elu.
__global__ void k_agg(const __half* __restrict__ h16, const float* __restrict__ asrc,
                      const float* __restrict__ adst, const int* __restrict__ rowst,
                      const int* __restrict__ col, const float* __restrict__ bias,
                      float* __restrict__ out, int n) {
    int wid = (int)((blockIdx.x * (size_t)blockDim.x + threadIdx.x) >> 6);
    if (wid >= n) return;
    int lane = threadIdx.x & 63;
    int g = lane >> 4;          // edge group 0..3
    int q = lane & 15;          // 16 lanes per edge; lane q -> channels 8q..8q+7
    int head = q >> 2;
    float ad = adst[wid * 4 + head];

    float acc[8] = {0.f, 0.f, 0.f, 0.f, 0.f, 0.f, 0.f, 0.f};
    float s = 0.f;

    if (g == 0) {  // self loop counted once (group 0)
        float w = lrelu_exp(asrc[wid * 4 + head] + ad);
        uint4 v = *reinterpret_cast<const uint4*>(h16 + (size_t)wid * 128 + q * 8);
        const __half2* hp = reinterpret_cast<const __half2*>(&v);
        s = w;
#pragma unroll
        for (int k = 0; k < 4; ++k) {
            float2 f = __half22float2(hp[k]);
            acc[2 * k]     += w * f.x;
            acc[2 * k + 1] += w * f.y;
        }
    }

    int beg = rowst[wid], end = rowst[wid + 1];
    int i = beg + g;
    for (; i + 4 < end; i += 8) {           // 2 edges in flight per group
        int s0 = col[i];
        int s1 = col[i + 4];
        float x0 = asrc[s0 * 4 + head];
        float x1 = asrc[s1 * 4 + head];
        uint4 v0 = *reinterpret_cast<const uint4*>(h16 + (size_t)s0 * 128 + q * 8);
        uint4 v1 = *reinterpret_cast<const uint4*>(h16 + (size_t)s1 * 128 + q * 8);
        float w0 = lrelu_exp(x0 + ad);
        float w1 = lrelu_exp(x1 + ad);
        s += w0 + w1;
        const __half2* h0 = reinterpret_cast<const __half2*>(&v0);
        const __half2* h1 = reinterpret_cast<const __half2*>(&v1);
#pragma unroll
        for (int k = 0; k < 4; ++k) {
            float2 f0 = __half22float2(h0[k]);
            float2 f1 = __half22float2(h1[k]);
            acc[2 * k]     += w0 * f0.x + w1 * f1.x;
            acc[2 * k + 1] += w0 * f0.y + w1 * f1.y;
        }
    }
    if (i < end) {                          // per-group tail (0 or 1 edge)
        int s0 = col[i];
        float w = lrelu_exp(asrc[s0 * 4 + head] + ad);
        uint4 v = *reinterpret_cast<const uint4*>(h16 + (size_t)s0 * 128 + q * 8);
        const __half2* hp = reinterpret_cast<const __half2*>(&v);
        s += w;
#pragma unroll
        for (int k = 0; k < 4; ++k) {
            float2 f = __half22float2(hp[k]);
            acc[2 * k]     += w * f.x;
            acc[2 * k + 1] += w * f.y;
        }
    }

    // combine the 4 groups (lanes q, q+16, q+32, q+48: same head & channels)
    s += __shfl_xor(s, 16, 64);
    s += __shfl_xor(s, 32, 64);
#pragma unroll
    for (int k = 0; k < 8; ++k) {
        acc[k] += __shfl_xor(acc[k], 16, 64);
        acc[k] += __shfl_xor(acc[k], 32, 64);
    }
    float inv = 1.f / s;
#pragma unroll
    for (int k = 0; k < 8; ++k) acc[k] *= inv;
    // head mean: heads on q>>2; sum lanes q, q^4, q^8 (xor 4 then 8)
#pragma unroll
    for (int k = 0; k < 8; ++k) {
        acc[k] += __shfl_xor(acc[k], 4, 64);
        acc[k] += __shfl_xor(acc[k], 8, 64);
    }
    if (lane < 4) {   // lane q holds final channels 8q..8q+7
        float o[8];
#pragma unroll
        for (int k = 0; k < 8; ++k) {
            float v = acc[k] * 0.25f + bias[lane * 8 + k];
            o[k] = v > 0.f ? v : (__expf(v) - 1.f);
        }
        float4* op = reinterpret_cast<float4*>(&out[(size_t)wid * 32 + lane * 8]);
        op[0] = make_float4(o[0], o[1], o[2], o[3]);
        op[1] = make_float4(o[4], o[5], o[6], o[7]);
    }
}

// ---------------- launch ----------------

extern "C" void kernel_launch(void* const* d_in, const int* in_sizes, int n_in,
                              void* d_out, int out_size, void* d_ws, size_t ws_size,
                              hipStream_t stream) {
    const float* x       = (const float*)d_in[0];
    const int*   ei      = (const int*)d_in[1];   // [2,E] int32
    const float* Ws      = (const float*)d_in[3]; // [3,32,128]
    const float* att_src = (const float*)d_in[4]; // [3,4,32]
    const float* att_dst = (const float*)d_in[5];
    const float* bias    = (const float*)d_in[6]; // [3,32]

    int N = in_sizes[0] / 32;
    int E = in_sizes[1] / 2;
    const int* srcv = ei;
    const int* dstv = ei + E;

    // workspace layout
    float* fws   = (float*)d_ws;
    __half* h16  = (__half*)fws;                        // N*128 halves
    float* asrc  = (float*)(h16 + (size_t)N * 128);     // N*4
    float* adst  = asrc + (size_t)N * 4;                // N*4
    float* xbuf  = adst + (size_t)N * 4;                // N*32
    int*   deg    = (int*)(xbuf + (size_t)N * 32);      // N
    int*   rowst  = deg + N;                            // N+1
    int*   bsums  = rowst + N + 1;                      // 512
    int*   boffs  = bsums + 512;                        // 512
    int*   col    = boffs + 512;                        // E
    int*   rank   = col + E;                            // E

    int nb256 = (N + 255) / 256;           // <=512 for scan2
    int gemmBlocks = (N + 63) / 64;
    int histBlocks = (E + 32 * 256 - 1) / (32 * 256);
    int scatBlocks = (E + 16 * 256 - 1) / (16 * 256);

    hipMemsetAsync(deg, 0, (size_t)N * sizeof(int), stream);

    for (int l = 0; l < 3; ++l) {
        const float* xin = (l == 0) ? x : xbuf;
        float* xout = (l == 2) ? (float*)d_out : xbuf;
        int extra = (l == 0) ? histBlocks : 0;
        k_gemm_alpha<<<gemmBlocks + extra, 256, 0, stream>>>(
            xin, Ws + (size_t)l * 32 * 128, att_src + l * 128, att_dst + l * 128,
            h16, asrc, adst, N, dstv, E, deg, rank, gemmBlocks);
        if (l == 0) {
            k_scan1<<<nb256, 256, 0, stream>>>(deg, N, bsums);
            k_scan2<<<1, 512, 0, stream>>>(bsums, nb256, boffs);
            k_scan3<<<nb256, 256, 0, stream>>>(deg, N, boffs, rowst);
            k_scatter<<<scatBlocks, 256, 0, stream>>>(srcv, dstv, rank, rowst, E, col);
        }
        k_agg<<<(N + 3) / 4, 256, 0, stream>>>(
            h16, asrc, adst, rowst, col, bias + l * 32, xout, N);
    }
}